// Round 12
// baseline (339.960 us; speedup 1.0000x reference)
//
#include <hip/hip_runtime.h>
#include <hip/hip_bf16.h>

typedef unsigned int uint;
typedef unsigned short ushortT;
typedef __attribute__((ext_vector_type(8))) short bf16x8;
typedef __attribute__((ext_vector_type(4))) float f32x4;

#define S_ 128
#define R_ 384
#define CM 256
#define CZ 128
#define H_ 8
#define D_ 32
#define SR (S_*R_)          // 49152
#define RRTOT (R_*R_)       // 147456
#define SHRD (S_*H_*R_*D_)  // 12582912 elements

__device__ __forceinline__ float bf2f(ushortT u) {
    return __uint_as_float(((uint)u) << 16);
}
__device__ __forceinline__ ushortT f2bf(float f) {
    uint x = __float_as_uint(f);
    x += 0x7FFFu + ((x >> 16) & 1u);   // RNE
    return (ushortT)(x >> 16);
}
__device__ __forceinline__ uint pack_bf2(float lo, float hi) {
    return (uint)f2bf(lo) | ((uint)f2bf(hi) << 16);
}

// ---------------------------------------------------------------------------
// K0: weight prep — transpose + bf16-ify all projection weights.
// ---------------------------------------------------------------------------
__global__ __launch_bounds__(256) void k_prep(
        const float* __restrict__ wq, const float* __restrict__ wk,
        const float* __restrict__ wv, const float* __restrict__ wg,
        const float* __restrict__ wo,
        ushortT* __restrict__ wt, ushortT* __restrict__ wgt,
        ushortT* __restrict__ wot) {
    int id = blockIdx.x * 256 + threadIdx.x;      // 5*65536 total
    int which = id >> 16, r16 = id & 65535;
    int y = r16 & 255, x = r16 >> 8;              // y = coalesced src fast dim
    if (which == 0)      wt[(size_t)y*256 + x]       = f2bf(wq[(size_t)x*256 + y] * 0.17677669529663687f);
    else if (which == 1) wt[(size_t)(256+y)*256 + x] = f2bf(wk[(size_t)x*256 + y]);
    else if (which == 2) wt[(size_t)(512+y)*256 + x] = f2bf(wv[(size_t)x*256 + y]);
    else if (which == 3) wgt[(size_t)y*256 + x]      = f2bf(wg[(size_t)x*256 + y]);
    else                 wot[(size_t)y*256 + x]      = f2bf(wo[(size_t)x*256 + y]);
}

// ---------------------------------------------------------------------------
// K1: pair LN + projection to z[h][i][j] (bf16). One wave per (i,j) row.
// ---------------------------------------------------------------------------
__global__ __launch_bounds__(256) void k_pair_bias(
        const float* __restrict__ pair, const float* __restrict__ pn_g,
        const float* __restrict__ pn_b, const float* __restrict__ w_pair,
        ushortT* __restrict__ z) {
    int wave = threadIdx.x >> 6, lane = threadIdx.x & 63;
    int row = blockIdx.x * 4 + wave;              // [0, R*R)
    const float* x = pair + (size_t)row * CZ;
    float2 xv = *(const float2*)&x[lane * 2];
    float s  = xv.x + xv.y;
    float s2 = xv.x*xv.x + xv.y*xv.y;
    #pragma unroll
    for (int off = 32; off; off >>= 1) {
        s  += __shfl_xor(s,  off);
        s2 += __shfl_xor(s2, off);
    }
    float mu  = s * (1.0f / 128.0f);
    float var = s2 * (1.0f / 128.0f) - mu * mu;
    float rstd = rsqrtf(var + 1e-5f);
    float2 gv = *(const float2*)&pn_g[lane * 2];
    float2 bv = *(const float2*)&pn_b[lane * 2];
    float n0 = (xv.x - mu) * rstd * gv.x + bv.x;
    float n1 = (xv.y - mu) * rstd * gv.y + bv.y;
    float4 wa = *(const float4*)&w_pair[lane*16     ];
    float4 wb = *(const float4*)&w_pair[lane*16 +  4];
    float4 wc = *(const float4*)&w_pair[lane*16 +  8];
    float4 wd = *(const float4*)&w_pair[lane*16 + 12];
    float v0_ = n0*wa.x + n1*wc.x, v1_ = n0*wa.y + n1*wc.y;
    float v2_ = n0*wa.z + n1*wc.z, v3_ = n0*wa.w + n1*wc.w;
    float v4_ = n0*wb.x + n1*wd.x, v5_ = n0*wb.y + n1*wd.y;
    float v6_ = n0*wb.z + n1*wd.z, v7_ = n0*wb.w + n1*wd.w;
    float x0 = __shfl_xor(v0_,1), x1 = __shfl_xor(v1_,1), x2 = __shfl_xor(v2_,1), x3 = __shfl_xor(v3_,1);
    float x4 = __shfl_xor(v4_,1), x5 = __shfl_xor(v5_,1), x6 = __shfl_xor(v6_,1), x7 = __shfl_xor(v7_,1);
    bool b0 = (lane & 1) != 0;
    float u0 = b0 ? v4_+x4 : v0_+x0;
    float u1 = b0 ? v5_+x5 : v1_+x1;
    float u2 = b0 ? v6_+x6 : v2_+x2;
    float u3 = b0 ? v7_+x7 : v3_+x3;
    float y0 = __shfl_xor(u0,2), y1 = __shfl_xor(u1,2), y2 = __shfl_xor(u2,2), y3 = __shfl_xor(u3,2);
    bool b1 = (lane & 2) != 0;
    float w0 = b1 ? u2+y2 : u0+y0;
    float w1 = b1 ? u3+y3 : u1+y1;
    float z0 = __shfl_xor(w0,4), z1 = __shfl_xor(w1,4);
    bool b2 = (lane & 4) != 0;
    float val = b2 ? w1+z1 : w0+z0;
    val += __shfl_xor(val, 8);
    val += __shfl_xor(val, 16);
    val += __shfl_xor(val, 32);
    int hmap = 4*(lane & 1) + 2*((lane >> 1) & 1) + ((lane >> 2) & 1);
    if (lane < 8) z[(size_t)hmap * RRTOT + row] = f2bf(val);
}

// ---------------------------------------------------------------------------
// LN reduce helper (E[x^2]-mu^2 fused butterfly) -> packed bf16 uint2
// ---------------------------------------------------------------------------
__device__ __forceinline__ uint2 ln_reduce(float4 xv, float4 gv, float4 bv) {
    float sm = (xv.x + xv.y) + (xv.z + xv.w);
    float s2 = (xv.x*xv.x + xv.y*xv.y) + (xv.z*xv.z + xv.w*xv.w);
    #pragma unroll
    for (int off = 32; off; off >>= 1) {
        sm += __shfl_xor(sm, off);
        s2 += __shfl_xor(s2, off);
    }
    float mu  = sm * (1.0f / 256.0f);
    float var = s2 * (1.0f / 256.0f) - mu * mu;
    float rstd = rsqrtf(var + 1e-5f);
    uint2 w;
    w.x = pack_bf2((xv.x - mu)*rstd*gv.x + bv.x, (xv.y - mu)*rstd*gv.y + bv.y);
    w.y = pack_bf2((xv.z - mu)*rstd*gv.z + bv.z, (xv.w - mu)*rstd*gv.w + bv.w);
    return w;
}

// ---------------------------------------------------------------------------
// K_LN: streaming LN of msa -> m (bf16, row-major [SR][256]).
// 8 row-loads hoisted per wave (high MLP), one 1KB load per row.
// ---------------------------------------------------------------------------
__global__ __launch_bounds__(256) void k_ln(
        const float* __restrict__ msa, const float* __restrict__ qn_g,
        const float* __restrict__ qn_b, ushortT* __restrict__ m) {
    int wave = threadIdx.x >> 6, lane = threadIdx.x & 63;
    int r0 = blockIdx.x * 32 + wave * 8;
    const float* src = msa + (size_t)r0 * CM + lane * 4;
    float4 x0 = *(const float4*)(src         );
    float4 x1 = *(const float4*)(src + 1*CM  );
    float4 x2 = *(const float4*)(src + 2*CM  );
    float4 x3 = *(const float4*)(src + 3*CM  );
    float4 x4 = *(const float4*)(src + 4*CM  );
    float4 x5 = *(const float4*)(src + 5*CM  );
    float4 x6 = *(const float4*)(src + 6*CM  );
    float4 x7 = *(const float4*)(src + 7*CM  );
    float4 gv = *(const float4*)&qn_g[lane*4];
    float4 bv = *(const float4*)&qn_b[lane*4];
    ushortT* dst = m + (size_t)r0 * CM + lane * 4;
    *(uint2*)(dst        ) = ln_reduce(x0, gv, bv);
    *(uint2*)(dst + 1*CM ) = ln_reduce(x1, gv, bv);
    *(uint2*)(dst + 2*CM ) = ln_reduce(x2, gv, bv);
    *(uint2*)(dst + 3*CM ) = ln_reduce(x3, gv, bv);
    *(uint2*)(dst + 4*CM ) = ln_reduce(x4, gv, bv);
    *(uint2*)(dst + 5*CM ) = ln_reduce(x5, gv, bv);
    *(uint2*)(dst + 6*CM ) = ln_reduce(x6, gv, bv);
    *(uint2*)(dst + 7*CM ) = ln_reduce(x7, gv, bv);
}

// ---------------------------------------------------------------------------
// 4-coltile MFMA group: 8 named accumulators, af vs weight base wb0 (+16/32/48
// tile strides). Returns via reference args.
// ---------------------------------------------------------------------------
#define MFMA_GROUP4(AF, WB)                                                          \
    {                                                                                \
        _Pragma("unroll")                                                            \
        for (int kc = 0; kc < 8; ++kc) {                                             \
            bf16x8 b0 = *(const bf16x8*)((WB) + kc*32);                              \
            bf16x8 b1 = *(const bf16x8*)((WB) + 16*256 + kc*32);                     \
            bf16x8 b2 = *(const bf16x8*)((WB) + 32*256 + kc*32);                     \
            bf16x8 b3 = *(const bf16x8*)((WB) + 48*256 + kc*32);                     \
            a0L = __builtin_amdgcn_mfma_f32_16x16x32_bf16(AF[0][kc], b0, a0L, 0,0,0);\
            a0H = __builtin_amdgcn_mfma_f32_16x16x32_bf16(AF[1][kc], b0, a0H, 0,0,0);\
            a1L = __builtin_amdgcn_mfma_f32_16x16x32_bf16(AF[0][kc], b1, a1L, 0,0,0);\
            a1H = __builtin_amdgcn_mfma_f32_16x16x32_bf16(AF[1][kc], b1, a1H, 0,0,0);\
            a2L = __builtin_amdgcn_mfma_f32_16x16x32_bf16(AF[0][kc], b2, a2L, 0,0,0);\
            a2H = __builtin_amdgcn_mfma_f32_16x16x32_bf16(AF[1][kc], b2, a2H, 0,0,0);\
            a3L = __builtin_amdgcn_mfma_f32_16x16x32_bf16(AF[0][kc], b3, a3L, 0,0,0);\
            a3H = __builtin_amdgcn_mfma_f32_16x16x32_bf16(AF[1][kc], b3, a3H, 0,0,0);\
        }                                                                            \
    }

// ---------------------------------------------------------------------------
// K_QKV: q/k/v projections from m. Row-split: wave owns 32 rows × all cols.
// A-fragments from global m; ZERO barriers (wave-private LDS staging; DS pipe
// is in-order per wave). Coalesced uint4 stores, r8-verified index math.
// ---------------------------------------------------------------------------
__global__ __launch_bounds__(256) void k_qkv(
        const ushortT* __restrict__ m, const ushortT* __restrict__ wt,
        ushortT* __restrict__ qo, ushortT* __restrict__ ko,
        ushortT* __restrict__ vto) {
    __shared__ ushortT st_sh[4 * 32 * 256];       // 16 KB per wave
    int tid = threadIdx.x, wave = tid >> 6, lane = tid & 63;
    int c = lane & 15, g = (lane >> 4) & 3;
    int r0 = blockIdx.x * 128, wrow = wave * 32;
    int s = r0 / R_, rl0 = r0 % R_ + wrow;        // block never crosses s (384 = 3*128)
    char* osb = (char*)st_sh + wave * 16384;

    bf16x8 af[2][8];
    #pragma unroll
    for (int rt = 0; rt < 2; ++rt)
        #pragma unroll
        for (int kc = 0; kc < 8; ++kc)
            af[rt][kc] = *(const bf16x8*)(m + (size_t)(r0 + wrow + rt*16 + c) * CM + kc*32 + 8*g);

    const f32x4 z4 = {0.f, 0.f, 0.f, 0.f};
    #pragma unroll
    for (int mI = 0; mI < 3; ++mI) {
        #pragma unroll
        for (int grp = 0; grp < 4; ++grp) {
            int tb = grp * 4;
            const ushortT* wb0 = wt + ((size_t)(mI*256 + tb*16 + c)) * 256 + 8*g;
            f32x4 a0L = z4, a0H = z4, a1L = z4, a1H = z4;
            f32x4 a2L = z4, a2H = z4, a3L = z4, a3H = z4;
            MFMA_GROUP4(af, wb0);
            #pragma unroll
            for (int j = 0; j < 4; ++j) {
                f32x4 lo = (j == 0) ? a0L : (j == 1) ? a1L : (j == 2) ? a2L : a3L;
                f32x4 hi = (j == 0) ? a0H : (j == 1) ? a1H : (j == 2) ? a2H : a3H;
                if (mI < 2) {
                    int col = (tb + j)*16 + c;
                    #pragma unroll
                    for (int r = 0; r < 4; ++r) {
                        int row0 = 4*g + r, row1 = row0 + 16;
                        *(ushortT*)(osb + ((row0*512 + col*2) ^ ((row0 & 7) << 4))) = f2bf(lo[r]);
                        *(ushortT*)(osb + ((row1*512 + col*2) ^ ((row1 & 7) << 4))) = f2bf(hi[r]);
                    }
                } else {
                    int hd = (tb + j)*16 + c;
                    #pragma unroll
                    for (int r = 0; r < 4; ++r) {
                        int rlo = 4*g + r, rhi = rlo + 16;
                        *(ushortT*)(osb + ((hd*64 + rlo*2) ^ ((hd & 3) << 4))) = f2bf(lo[r]);
                        *(ushortT*)(osb + ((hd*64 + rhi*2) ^ ((hd & 3) << 4))) = f2bf(hi[r]);
                    }
                }
            }
        }
        // wave-private readback + coalesced store (in-order DS pipe: no barrier)
        if (mI < 2) {
            ushortT* O = (mI == 0) ? qo : ko;
            #pragma unroll
            for (int i = 0; i < 16; ++i) {
                int chunk = lane + i*64;          // 1024 16B chunks in region
                int row = chunk >> 5, c16 = chunk & 31;
                uint4 vd = *(const uint4*)(osb + ((row*512 + c16*16) ^ ((row & 7) << 4)));
                int hh = c16 >> 2, dq = (c16 & 3) * 8;
                size_t ga = ((size_t)(s*H_ + hh) * R_ + rl0 + row) * D_ + dq;
                *(uint4*)&O[ga] = vd;
            }
        } else {
            #pragma unroll
            for (int i = 0; i < 16; ++i) {
                int chunk = lane + i*64;
                int hd = chunk >> 2, q8 = chunk & 3;
                uint4 vd = *(const uint4*)(osb + ((hd*64 + q8*16) ^ ((hd & 3) << 4)));
                size_t ga = ((size_t)(s*256 + hd)) * R_ + rl0 + q8*8;
                *(uint4*)&vto[ga] = vd;
            }
        }
    }
}

// ---------------------------------------------------------------------------
// K_OUT_M: gating + output projection, row-split, reads m (no LN, no msa).
// Wave owns 32 rows end-to-end; og staged wave-private; ZERO barriers.
// ---------------------------------------------------------------------------
__global__ __launch_bounds__(256) void k_out_m(
        const ushortT* __restrict__ m, const ushortT* __restrict__ wgt,
        const float* __restrict__ bg, const ushortT* __restrict__ wot,
        const float* __restrict__ bo, float* __restrict__ out) {
    __shared__ ushortT og_sh[4 * 32 * 256];       // 16 KB per wave
    int tid = threadIdx.x, wave = tid >> 6, lane = tid & 63;
    int c = lane & 15, g = (lane >> 4) & 3;
    int r0 = blockIdx.x * 128, wrow = wave * 32;
    char* ogb = (char*)og_sh + wave * 16384;

    bf16x8 af[2][8];
    #pragma unroll
    for (int rt = 0; rt < 2; ++rt)
        #pragma unroll
        for (int kc = 0; kc < 8; ++kc)
            af[rt][kc] = *(const bf16x8*)(m + (size_t)(r0 + wrow + rt*16 + c) * CM + kc*32 + 8*g);

    const f32x4 z4 = {0.f, 0.f, 0.f, 0.f};
    // GEMM-g + sigmoid gate * o -> og (wave-private staged)
    #pragma unroll
    for (int grp = 0; grp < 4; ++grp) {
        int tb = grp * 4;
        const ushortT* wb0 = wgt + (size_t)(tb*16 + c) * 256 + 8*g;
        f32x4 a0L = z4, a0H = z4, a1L = z4, a1H = z4;
        f32x4 a2L = z4, a2H = z4, a3L = z4, a3H = z4;
        MFMA_GROUP4(af, wb0);
        #pragma unroll
        for (int j = 0; j < 4; ++j) {
            f32x4 lo = (j == 0) ? a0L : (j == 1) ? a1L : (j == 2) ? a2L : a3L;
            f32x4 hi = (j == 0) ? a0H : (j == 1) ? a1H : (j == 2) ? a2H : a3H;
            int t = (tb + j)*16 + c;
            float bgv = bg[t];
            #pragma unroll
            for (int r = 0; r < 4; ++r) {
                int row0 = 4*g + r, row1 = row0 + 16;
                float g0 = 1.0f / (1.0f + __expf(-(lo[r] + bgv)));
                float g1 = 1.0f / (1.0f + __expf(-(hi[r] + bgv)));
                float ov0 = out[(size_t)(r0 + wrow + row0) * CM + t];
                float ov1 = out[(size_t)(r0 + wrow + row1) * CM + t];
                *(ushortT*)(ogb + ((row0*512 + t*2) ^ ((row0 & 7) << 4))) = f2bf(ov0 * g0);
                *(ushortT*)(ogb + ((row1*512 + t*2) ^ ((row1 & 7) << 4))) = f2bf(ov1 * g1);
            }
        }
    }

    bf16x8 af2[2][8];                             // in-order DS pipe: no barrier
    #pragma unroll
    for (int rt = 0; rt < 2; ++rt)
        #pragma unroll
        for (int kc = 0; kc < 8; ++kc) {
            int row = rt*16 + c;
            af2[rt][kc] = *(const bf16x8*)(ogb + ((row*512 + (kc*32 + 8*g)*2) ^ ((c & 7) << 4)));
        }

    #pragma unroll
    for (int grp = 0; grp < 4; ++grp) {
        int tb = grp * 4;
        const ushortT* wb0 = wot + (size_t)(tb*16 + c) * 256 + 8*g;
        f32x4 a0L = z4, a0H = z4, a1L = z4, a1H = z4;
        f32x4 a2L = z4, a2H = z4, a3L = z4, a3H = z4;
        MFMA_GROUP4(af2, wb0);
        #pragma unroll
        for (int j = 0; j < 4; ++j) {
            f32x4 lo = (j == 0) ? a0L : (j == 1) ? a1L : (j == 2) ? a2L : a3L;
            f32x4 hi = (j == 0) ? a0H : (j == 1) ? a1H : (j == 2) ? a2H : a3H;
            int t = (tb + j)*16 + c;
            float bov = bo[t];
            #pragma unroll
            for (int r = 0; r < 4; ++r) {
                int row0 = 4*g + r, row1 = row0 + 16;
                out[(size_t)(r0 + wrow + row0) * CM + t] = lo[r] + bov;
                out[(size_t)(r0 + wrow + row1) * CM + t] = hi[r] + bov;
            }
        }
    }
}

// ---------------------------------------------------------------------------
// FALLBACK kernels (r10-verified) if ws_size is too small for m.
// ---------------------------------------------------------------------------
__device__ __forceinline__ void ln_row_f4(
        const float* __restrict__ src, const float* __restrict__ gam,
        const float* __restrict__ bet, char* msb, int row, int lane) {
    float4 xv = *(const float4*)&src[lane * 4];
    float4 gv = *(const float4*)&gam[lane * 4];
    float4 bv = *(const float4*)&bet[lane * 4];
    uint2 w = ln_reduce(xv, gv, bv);
    *(uint2*)(msb + ((row*512 + lane*8) ^ ((row & 7) << 4))) = w;
}

__global__ __launch_bounds__(256) void k_msa_qkv_fb(
        const float* __restrict__ msa, const float* __restrict__ qn_g,
        const float* __restrict__ qn_b, const ushortT* __restrict__ wt,
        ushortT* __restrict__ qo, ushortT* __restrict__ ko,
        ushortT* __restrict__ vto) {
    __shared__ ushortT m_sh[32 * 256];
    __shared__ ushortT st_sh[3 * 32 * 256];
    int tid = threadIdx.x, wave = tid >> 6, lane = tid & 63;
    int c = lane & 15, g = (lane >> 4) & 3;
    int r0 = blockIdx.x * 32, s = r0 / R_, rl0 = r0 % R_;
    char* msb = (char*)m_sh;
    char* stb = (char*)st_sh;
    #pragma unroll
    for (int i = 0; i < 8; ++i)
        ln_row_f4(msa + (size_t)(r0 + wave*8 + i) * CM, qn_g, qn_b, msb, wave*8 + i, lane);
    __syncthreads();
    bf16x8 af[2][8];
    #pragma unroll
    for (int rt = 0; rt < 2; ++rt)
        #pragma unroll
        for (int kc = 0; kc < 8; ++kc) {
            int row = rt*16 + c;
            af[rt][kc] = *(const bf16x8*)(msb + ((row*512 + (kc*32 + 8*g)*2) ^ ((c & 7) << 4)));
        }
    const f32x4 z4 = {0.f, 0.f, 0.f, 0.f};
    #pragma unroll
    for (int mI = 0; mI < 3; ++mI) {
        char* osb = stb + mI * 16384;
        int tb = wave * 4;
        const ushortT* wb0 = wt + ((size_t)(mI*256 + tb*16 + c)) * 256 + 8*g;
        f32x4 a0L = z4, a0H = z4, a1L = z4, a1H = z4;
        f32x4 a2L = z4, a2H = z4, a3L = z4, a3H = z4;
        MFMA_GROUP4(af, wb0);
        #pragma unroll
        for (int j = 0; j < 4; ++j) {
            f32x4 lo = (j == 0) ? a0L : (j == 1) ? a1L : (j == 2) ? a2L : a3L;
            f32x4 hi = (j == 0) ? a0H : (j == 1) ? a1H : (j == 2) ? a2H : a3H;
            if (mI < 2) {
                int col = (tb + j)*16 + c;
                #pragma unroll
                for (int r = 0; r < 4; ++r) {
                    int row0 = 4*g + r, row1 = row0 + 16;
                    *(ushortT*)(osb + ((row0*512 + col*2) ^ ((row0 & 7) << 4))) = f2bf(lo[r]);
                    *(ushortT*)(osb + ((row1*512 + col*2) ^ ((row1 & 7) << 4))) = f2bf(hi[r]);
                }
            } else {
                int hd = (tb + j)*16 + c;
                #pragma unroll
                for (int r = 0; r < 4; ++r) {
                    int rlo = 4*g + r, rhi = rlo + 16;
                    *(ushortT*)(osb + ((hd*64 + rlo*2) ^ ((hd & 3) << 4))) = f2bf(lo[r]);
                    *(ushortT*)(osb + ((hd*64 + rhi*2) ^ ((hd & 3) << 4))) = f2bf(hi[r]);
                }
            }
        }
    }
    __syncthreads();
    #pragma unroll
    for (int mm = 0; mm < 2; ++mm) {
        char* osb = stb + mm * 16384;
        ushortT* O = (mm == 0) ? qo : ko;
        #pragma unroll
        for (int i = 0; i < 4; ++i) {
            int idx = tid + i*256;
            int row = idx >> 5, c16 = idx & 31;
            uint4 vd = *(const uint4*)(osb + ((row*512 + c16*16) ^ ((row & 7) << 4)));
            int hh = c16 >> 2, dq = (c16 & 3) * 8;
            size_t ga = ((size_t)(s*H_ + hh) * R_ + rl0 + row) * D_ + dq;
            *(uint4*)&O[ga] = vd;
        }
    }
    {
        char* osb = stb + 2 * 16384;
        #pragma unroll
        for (int i = 0; i < 4; ++i) {
            int idx = tid + i*256;
            int hd = idx >> 2, q8 = idx & 3;
            uint4 vd = *(const uint4*)(osb + ((hd*64 + q8*16) ^ ((hd & 3) << 4)));
            size_t ga = ((size_t)(s*256 + hd)) * R_ + rl0 + q8*8;
            *(uint4*)&vto[ga] = vd;
        }
    }
}

__global__ __launch_bounds__(256) void k_out_fb(
        const float* __restrict__ msa, const float* __restrict__ qn_g,
        const float* __restrict__ qn_b, const ushortT* __restrict__ wgt,
        const float* __restrict__ bg, const ushortT* __restrict__ wot,
        const float* __restrict__ bo, float* __restrict__ out) {
    __shared__ ushortT m_sh[32 * 256];
    __shared__ ushortT og_sh[32 * 256];
    int tid = threadIdx.x, wave = tid >> 6, lane = tid & 63;
    int c = lane & 15, g = (lane >> 4) & 3;
    int r0 = blockIdx.x * 32;
    char* msb = (char*)m_sh;
    char* ogb = (char*)og_sh;
    #pragma unroll
    for (int i = 0; i < 8; ++i)
        ln_row_f4(msa + (size_t)(r0 + wave*8 + i) * CM, qn_g, qn_b, msb, wave*8 + i, lane);
    __syncthreads();
    bf16x8 af[2][8];
    #pragma unroll
    for (int rt = 0; rt < 2; ++rt)
        #pragma unroll
        for (int kc = 0; kc < 8; ++kc) {
            int row = rt*16 + c;
            af[rt][kc] = *(const bf16x8*)(msb + ((row*512 + (kc*32 + 8*g)*2) ^ ((c & 7) << 4)));
        }
    const f32x4 z4 = {0.f, 0.f, 0.f, 0.f};
    {
        int tb = wave * 4;
        const ushortT* wb0 = wgt + (size_t)(tb*16 + c) * 256 + 8*g;
        f32x4 a0L = z4, a0H = z4, a1L = z4, a1H = z4;
        f32x4 a2L = z4, a2H = z4, a3L = z4, a3H = z4;
        MFMA_GROUP4(af, wb0);
        #pragma unroll
        for (int j = 0; j < 4; ++j) {
            f32x4 lo = (j == 0) ? a0L : (j == 1) ? a1L : (j == 2) ? a2L : a3L;
            f32x4 hi = (j == 0) ? a0H : (j == 1) ? a1H : (j == 2) ? a2H : a3H;
            int t = (tb + j)*16 + c;
            float bgv = bg[t];
            #pragma unroll
            for (int r = 0; r < 4; ++r) {
                int row0 = 4*g + r, row1 = row0 + 16;
                float g0 = 1.0f / (1.0f + __expf(-(lo[r] + bgv)));
                float g1 = 1.0f / (1.0f + __expf(-(hi[r] + bgv)));
                float ov0 = out[(size_t)(r0 + row0) * CM + t];
                float ov1 = out[(size_t)(r0 + row1) * CM + t];
                *(ushortT*)(ogb + ((row0*512 + t*2) ^ ((row0 & 7) << 4))) = f2bf(ov0 * g0);
                *(ushortT*)(ogb + ((row1*512 + t*2) ^ ((row1 & 7) << 4))) = f2bf(ov1 * g1);
            }
        }
    }
    __syncthreads();
    bf16x8 af2[2][8];
    #pragma unroll
    for (int rt = 0; rt < 2; ++rt)
        #pragma unroll
        for (int kc = 0; kc < 8; ++kc) {
            int row = rt*16 + c;
            af2[rt][kc] = *(const bf16x8*)(ogb + ((row*512 + (kc*32 + 8*g)*2) ^ ((c & 7) << 4)));
        }
    {
        int tb = wave * 4;
        const ushortT* wb0 = wot + (size_t)(tb*16 + c) * 256 + 8*g;
        f32x4 a0L = z4, a0H = z4, a1L = z4, a1H = z4;
        f32x4 a2L = z4, a2H = z4, a3L = z4, a3H = z4;
        MFMA_GROUP4(af2, wb0);
        #pragma unroll
        for (int j = 0; j < 4; ++j) {
            f32x4 lo = (j == 0) ? a0L : (j == 1) ? a1L : (j == 2) ? a2L : a3L;
            f32x4 hi = (j == 0) ? a0H : (j == 1) ? a1H : (j == 2) ? a2H : a3H;
            int t = (tb + j)*16 + c;
            float bov = bo[t];
            #pragma unroll
            for (int r = 0; r < 4; ++r) {
                int row0 = 4*g + r, row1 = row0 + 16;
                out[(size_t)(r0 + row0) * CM + t] = lo[r] + bov;
                out[(size_t)(r0 + row1) * CM + t] = hi[r] + bov;
            }
        }
    }
}

// ---------------------------------------------------------------------------
// K3: attention per (s,h), MFMA (r10-verified: unroll-2 kb loop, 80B K rows,
// parity P slab; grid S_*H_).
// ---------------------------------------------------------------------------
__global__ __launch_bounds__(512) void k_attn(
        const ushortT* __restrict__ qws, const ushortT* __restrict__ kws,
        const ushortT* __restrict__ vtws, const ushortT* __restrict__ zws,
        const float* __restrict__ mask, float* __restrict__ out) {
    __shared__ ushortT k_sh[R_ * 40];
    __shared__ ushortT vt_sh[D_ * R_];
    __shared__ float   mb[R_];
    __shared__ ushortT p_sh[8 * 1280];
    int tid = threadIdx.x, wave = tid >> 6, lane = tid & 63;
    int c = lane & 15, g = (lane >> 4) & 3;
    int s = blockIdx.x >> 3, h = blockIdx.x & 7;
    size_t base = (size_t)(s * H_ + h) * R_ * D_;

    {
        const uint4* ks = (const uint4*)(kws + base);
        char* kb_ = (char*)k_sh;
        for (int i = tid; i < 1536; i += 512) {
            int row = i >> 2, part = i & 3;
            *(uint4*)(kb_ + row*80 + part*16) = ks[i];
        }
        const uint4* vs = (const uint4*)(vtws + base);
        char* vb = (char*)vt_sh;
        for (int i = tid; i < 1536; i += 512) {
            int d = i / 48, ch = i % 48;
            *(uint4*)(vb + ((d*768 + ch*16) ^ ((d & 7) << 4))) = vs[i];
        }
        for (int j = tid; j < R_; j += 512) mb[j] = 1e9f * (mask[s*R_ + j] - 1.0f);
    }
    __syncthreads();

    const char* ksb = (const char*)k_sh;
    const char* vtb = (const char*)vt_sh;
    char* psb = (char*)p_sh + wave * 2560;
    const f32x4 zero4 = {0.f, 0.f, 0.f, 0.f};

    for (int qt = wave; qt < 24; qt += 8) {
        int q0 = qt * 16;
        bf16x8 qf = *(const bf16x8*)(qws + base + (size_t)(q0 + c) * D_ + 8*g);
        const ushortT* zq = zws + (size_t)h * RRTOT + (size_t)(q0 + c) * R_ + 4*g;

        float sm = 0.f;
        f32x4 o0 = zero4, o1 = zero4;
        #pragma unroll 2
        for (int kb = 0; kb < 12; ++kb) {
            bf16x8 kfA = *(const bf16x8*)(ksb + ((2*kb    )*16 + c)*80 + 16*g);
            bf16x8 kfB = *(const bf16x8*)(ksb + ((2*kb + 1)*16 + c)*80 + 16*g);
            f32x4 pA = __builtin_amdgcn_mfma_f32_16x16x32_bf16(kfA, qf, zero4, 0, 0, 0);
            f32x4 pB = __builtin_amdgcn_mfma_f32_16x16x32_bf16(kfB, qf, zero4, 0, 0, 0);
            float4 mvA = *(const float4*)&mb[(2*kb    )*16 + 4*g];
            float4 mvB = *(const float4*)&mb[(2*kb + 1)*16 + 4*g];
            ushort4 zvA = *(const ushort4*)(zq + (2*kb    )*16);
            ushort4 zvB = *(const ushort4*)(zq + (2*kb + 1)*16);
            pA.x = __expf(pA.x + mvA.x + bf2f(zvA.x));
            pA.y = __expf(pA.y + mvA.y + bf2f(zvA.y));
            pA.z = __expf(pA.z + mvA.z + bf2f(zvA.z));
            pA.w = __expf(pA.w + mvA.w + bf2f(zvA.w));
            pB.x = __expf(pB.x + mvB.x + bf2f(zvB.x));
            pB.y = __expf(pB.y + mvB.y + bf2f(zvB.y));
            pB.z = __expf(pB.z + mvB.z + bf2f(zvB.z));
            pB.w = __expf(pB.w + mvB.w + bf2f(zvB.w));
            sm += (pA.x + pA.y) + (pA.z + pA.w) + (pB.x + pB.y) + (pB.z + pB.w);
            uint2 wA; wA.x = pack_bf2(pA.x, pA.y); wA.y = pack_bf2(pA.z, pA.w);
            uint2 wB; wB.x = pack_bf2(pB.x, pB.y); wB.y = pack_bf2(pB.z, pB.w);
            *(uint2*)(psb + (kb&1)*1280 + c*80 +      8*g) = wA;
            *(uint2*)(psb + (kb&1)*1280 + c*80 + 32 + 8*g) = wB;
            bf16x8 pa = *(const bf16x8*)(psb + (kb&1)*1280 + c*80 + 16*g);
            bf16x8 v0 = *(const bf16x8*)(vtb + (((c     )*768 + kb*64 + 16*g) ^ ((c & 7) << 4)));
            bf16x8 v1 = *(const bf16x8*)(vtb + (((16 + c)*768 + kb*64 + 16*g) ^ ((c & 7) << 4)));
            o0 = __builtin_amdgcn_mfma_f32_16x16x32_bf16(v0, pa, o0, 0, 0, 0);
            o1 = __builtin_amdgcn_mfma_f32_16x16x32_bf16(v1, pa, o1, 0, 0, 0);
        }
        sm += __shfl_xor(sm, 16);
        sm += __shfl_xor(sm, 32);
        float inv = 1.0f / sm;
        float4 s0, s1;
        s0.x = o0[0]*inv; s0.y = o0[1]*inv; s0.z = o0[2]*inv; s0.w = o0[3]*inv;
        s1.x = o1[0]*inv; s1.y = o1[1]*inv; s1.z = o1[2]*inv; s1.w = o1[3]*inv;
        float* ob = out + (size_t)(s*R_ + q0 + c) * CM + h*D_ + 4*g;
        *(float4*)ob = s0;
        *(float4*)(ob + 16) = s1;
    }
}

// ---------------------------------------------------------------------------
extern "C" void kernel_launch(void* const* d_in, const int* in_sizes, int n_in,
                              void* d_out, int out_size, void* d_ws, size_t ws_size,
                              hipStream_t stream) {
    const float* msa    = (const float*)d_in[0];
    const float* pair   = (const float*)d_in[1];
    const float* mask   = (const float*)d_in[2];
    const float* qn_g   = (const float*)d_in[3];
    const float* qn_b   = (const float*)d_in[4];
    const float* pn_g   = (const float*)d_in[5];
    const float* pn_b   = (const float*)d_in[6];
    const float* w_pair = (const float*)d_in[7];
    const float* wq     = (const float*)d_in[8];
    const float* wk     = (const float*)d_in[9];
    const float* wv     = (const float*)d_in[10];
    const float* wg     = (const float*)d_in[11];
    const float* bg     = (const float*)d_in[12];
    const float* wo     = (const float*)d_in[13];
    const float* bo     = (const float*)d_in[14];
    float* out = (float*)d_out;

    ushortT* qws  = (ushortT*)d_ws;
    ushortT* kws  = qws + (size_t)SHRD;
    ushortT* vtws = kws + (size_t)SHRD;
    ushortT* zws  = vtws + (size_t)SHRD;
    ushortT* wt   = zws + (size_t)H_ * RRTOT;
    ushortT* wgt  = wt + 3 * 65536;
    ushortT* wot  = wgt + 65536;
    ushortT* mws  = wot + 65536;                  // [SR][256] bf16, +25.2 MB

    size_t need = ((size_t)3*SHRD + (size_t)H_*RRTOT + 5*65536 + (size_t)SR*CM) * 2;

    k_prep     <<<1280,    256, 0, stream>>>(wq, wk, wv, wg, wo, wt, wgt, wot);
    k_pair_bias<<<RRTOT/4, 256, 0, stream>>>(pair, pn_g, pn_b, w_pair, zws);
    if (ws_size >= need) {
        k_ln   <<<SR/32,   256, 0, stream>>>(msa, qn_g, qn_b, mws);
        k_qkv  <<<SR/128,  256, 0, stream>>>(mws, wt, qws, kws, vtws);
        k_attn <<<S_*H_,   512, 0, stream>>>(qws, kws, vtws, zws, mask, out);
        k_out_m<<<SR/128,  256, 0, stream>>>(mws, wgt, bg, wot, bo, out);
    } else {
        k_msa_qkv_fb<<<SR/32, 256, 0, stream>>>(msa, qn_g, qn_b, wt, qws, kws, vtws);
        k_attn      <<<S_*H_, 512, 0, stream>>>(qws, kws, vtws, zws, mask, out);
        k_out_fb    <<<SR/32, 256, 0, stream>>>(msa, qn_g, qn_b, wgt, bg, wot, bo, out);
    }
}

// Round 13
// 291.786 us; speedup vs baseline: 1.1651x; 1.1651x over previous
//
#include <hip/hip_runtime.h>
#include <hip/hip_bf16.h>

typedef unsigned int uint;
typedef unsigned short ushortT;
typedef __attribute__((ext_vector_type(8))) short bf16x8;
typedef __attribute__((ext_vector_type(4))) float f32x4;

#define S_ 128
#define R_ 384
#define CM 256
#define CZ 128
#define H_ 8
#define D_ 32
#define SR (S_*R_)          // 49152
#define RRTOT (R_*R_)       // 147456

__device__ __forceinline__ float bf2f(ushortT u) {
    return __uint_as_float(((uint)u) << 16);
}
__device__ __forceinline__ ushortT f2bf(float f) {
    uint x = __float_as_uint(f);
    x += 0x7FFFu + ((x >> 16) & 1u);   // RNE
    return (ushortT)(x >> 16);
}
__device__ __forceinline__ uint pack_bf2(float lo, float hi) {
    return (uint)f2bf(lo) | ((uint)f2bf(hi) << 16);
}

// ---------------------------------------------------------------------------
// K0: weight prep — transpose + bf16-ify all projection weights.
// wt[mI*256 + t][c] = w_mI[c][t]; mI=0 q-scaled, 1 k, 2 v. wgt/wot likewise.
// ---------------------------------------------------------------------------
__global__ __launch_bounds__(256) void k_prep(
        const float* __restrict__ wq, const float* __restrict__ wk,
        const float* __restrict__ wv, const float* __restrict__ wg,
        const float* __restrict__ wo,
        ushortT* __restrict__ wt, ushortT* __restrict__ wgt,
        ushortT* __restrict__ wot) {
    int id = blockIdx.x * 256 + threadIdx.x;      // 5*65536 total
    int which = id >> 16, r16 = id & 65535;
    int y = r16 & 255, x = r16 >> 8;              // y = coalesced src fast dim
    if (which == 0)      wt[(size_t)y*256 + x]       = f2bf(wq[(size_t)x*256 + y] * 0.17677669529663687f);
    else if (which == 1) wt[(size_t)(256+y)*256 + x] = f2bf(wk[(size_t)x*256 + y]);
    else if (which == 2) wt[(size_t)(512+y)*256 + x] = f2bf(wv[(size_t)x*256 + y]);
    else if (which == 3) wgt[(size_t)y*256 + x]      = f2bf(wg[(size_t)x*256 + y]);
    else                 wot[(size_t)y*256 + x]      = f2bf(wo[(size_t)x*256 + y]);
}

// ---------------------------------------------------------------------------
// K1: pair LN + projection to z[h][i][j] (bf16). One wave per (i,j) row.
// ---------------------------------------------------------------------------
__global__ __launch_bounds__(256) void k_pair_bias(
        const float* __restrict__ pair, const float* __restrict__ pn_g,
        const float* __restrict__ pn_b, const float* __restrict__ w_pair,
        ushortT* __restrict__ z) {
    int wave = threadIdx.x >> 6, lane = threadIdx.x & 63;
    int row = blockIdx.x * 4 + wave;              // [0, R*R)
    const float* x = pair + (size_t)row * CZ;
    float2 xv = *(const float2*)&x[lane * 2];
    float s  = xv.x + xv.y;
    float s2 = xv.x*xv.x + xv.y*xv.y;
    #pragma unroll
    for (int off = 32; off; off >>= 1) {
        s  += __shfl_xor(s,  off);
        s2 += __shfl_xor(s2, off);
    }
    float mu  = s * (1.0f / 128.0f);
    float var = s2 * (1.0f / 128.0f) - mu * mu;
    float rstd = rsqrtf(var + 1e-5f);
    float2 gv = *(const float2*)&pn_g[lane * 2];
    float2 bv = *(const float2*)&pn_b[lane * 2];
    float n0 = (xv.x - mu) * rstd * gv.x + bv.x;
    float n1 = (xv.y - mu) * rstd * gv.y + bv.y;
    float4 wa = *(const float4*)&w_pair[lane*16     ];
    float4 wb = *(const float4*)&w_pair[lane*16 +  4];
    float4 wc = *(const float4*)&w_pair[lane*16 +  8];
    float4 wd = *(const float4*)&w_pair[lane*16 + 12];
    float v0_ = n0*wa.x + n1*wc.x, v1_ = n0*wa.y + n1*wc.y;
    float v2_ = n0*wa.z + n1*wc.z, v3_ = n0*wa.w + n1*wc.w;
    float v4_ = n0*wb.x + n1*wd.x, v5_ = n0*wb.y + n1*wd.y;
    float v6_ = n0*wb.z + n1*wd.z, v7_ = n0*wb.w + n1*wd.w;
    float x0 = __shfl_xor(v0_,1), x1 = __shfl_xor(v1_,1), x2 = __shfl_xor(v2_,1), x3 = __shfl_xor(v3_,1);
    float x4 = __shfl_xor(v4_,1), x5 = __shfl_xor(v5_,1), x6 = __shfl_xor(v6_,1), x7 = __shfl_xor(v7_,1);
    bool b0 = (lane & 1) != 0;
    float u0 = b0 ? v4_+x4 : v0_+x0;
    float u1 = b0 ? v5_+x5 : v1_+x1;
    float u2 = b0 ? v6_+x6 : v2_+x2;
    float u3 = b0 ? v7_+x7 : v3_+x3;
    float y0 = __shfl_xor(u0,2), y1 = __shfl_xor(u1,2), y2 = __shfl_xor(u2,2), y3 = __shfl_xor(u3,2);
    bool b1 = (lane & 2) != 0;
    float w0 = b1 ? u2+y2 : u0+y0;
    float w1 = b1 ? u3+y3 : u1+y1;
    float z0 = __shfl_xor(w0,4), z1 = __shfl_xor(w1,4);
    bool b2 = (lane & 4) != 0;
    float val = b2 ? w1+z1 : w0+z0;
    val += __shfl_xor(val, 8);
    val += __shfl_xor(val, 16);
    val += __shfl_xor(val, 32);
    int hmap = 4*(lane & 1) + 2*((lane >> 1) & 1) + ((lane >> 2) & 1);
    if (lane < 8) z[(size_t)hmap * RRTOT + row] = f2bf(val);
}

// ---------------------------------------------------------------------------
// LN reduce helper (E[x^2]-mu^2 fused butterfly) -> packed bf16 uint2
// ---------------------------------------------------------------------------
__device__ __forceinline__ uint2 ln_reduce(float4 xv, float4 gv, float4 bv) {
    float sm = (xv.x + xv.y) + (xv.z + xv.w);
    float s2 = (xv.x*xv.x + xv.y*xv.y) + (xv.z*xv.z + xv.w*xv.w);
    #pragma unroll
    for (int off = 32; off; off >>= 1) {
        sm += __shfl_xor(sm, off);
        s2 += __shfl_xor(s2, off);
    }
    float mu  = sm * (1.0f / 256.0f);
    float var = s2 * (1.0f / 256.0f) - mu * mu;
    float rstd = rsqrtf(var + 1e-5f);
    uint2 w;
    w.x = pack_bf2((xv.x - mu)*rstd*gv.x + bv.x, (xv.y - mu)*rstd*gv.y + bv.y);
    w.y = pack_bf2((xv.z - mu)*rstd*gv.z + bv.z, (xv.w - mu)*rstd*gv.w + bv.w);
    return w;
}

// ---------------------------------------------------------------------------
// K_LN: streaming LN of msa -> m (bf16, row-major [SR][256]). (r12-verified)
// ---------------------------------------------------------------------------
__global__ __launch_bounds__(256) void k_ln(
        const float* __restrict__ msa, const float* __restrict__ qn_g,
        const float* __restrict__ qn_b, ushortT* __restrict__ m) {
    int wave = threadIdx.x >> 6, lane = threadIdx.x & 63;
    int r0 = blockIdx.x * 32 + wave * 8;
    const float* src = msa + (size_t)r0 * CM + lane * 4;
    float4 x0 = *(const float4*)(src        );
    float4 x1 = *(const float4*)(src + 1*CM );
    float4 x2 = *(const float4*)(src + 2*CM );
    float4 x3 = *(const float4*)(src + 3*CM );
    float4 x4 = *(const float4*)(src + 4*CM );
    float4 x5 = *(const float4*)(src + 5*CM );
    float4 x6 = *(const float4*)(src + 6*CM );
    float4 x7 = *(const float4*)(src + 7*CM );
    float4 gv = *(const float4*)&qn_g[lane*4];
    float4 bv = *(const float4*)&qn_b[lane*4];
    ushortT* dst = m + (size_t)r0 * CM + lane * 4;
    *(uint2*)(dst       ) = ln_reduce(x0, gv, bv);
    *(uint2*)(dst + 1*CM) = ln_reduce(x1, gv, bv);
    *(uint2*)(dst + 2*CM) = ln_reduce(x2, gv, bv);
    *(uint2*)(dst + 3*CM) = ln_reduce(x3, gv, bv);
    *(uint2*)(dst + 4*CM) = ln_reduce(x4, gv, bv);
    *(uint2*)(dst + 5*CM) = ln_reduce(x5, gv, bv);
    *(uint2*)(dst + 6*CM) = ln_reduce(x6, gv, bv);
    *(uint2*)(dst + 7*CM) = ln_reduce(x7, gv, bv);
}

// ---------------------------------------------------------------------------
// K3f: FUSED q/k/v projection + attention, per (s,h). 8 waves.
// Phase 1: each wave GEMMs its 48 rows of K and V for head h straight into
//   the verified k_sh (80B pitch [k][d]) / vt_sh ([d][k], XOR (d&7)<<4)
//   layouts using the m89 C-frag mapping (row=4g+r, col=c).  One barrier.
// Phase 2: per q-tile, 16-MFMA q-GEMM staged through p-slab buffer 0 (idle
//   before the kb loop), read back as the verified qf B-fragment; then the
//   r6/r10-verified kb attention loop, unchanged.
// Eliminates k_msa_qkv and the 150 MB q/k/vt ws round-trip.
// ---------------------------------------------------------------------------
__global__ __launch_bounds__(512) void k_attn_f(
        const ushortT* __restrict__ m, const ushortT* __restrict__ wt,
        const ushortT* __restrict__ zws, const float* __restrict__ mask,
        float* __restrict__ out) {
    __shared__ ushortT k_sh[R_ * 40];             // [k][d] rows padded to 80 B
    __shared__ ushortT vt_sh[D_ * R_];            // [d][k] XOR ((d&7)<<4)
    __shared__ float   mb[R_];
    __shared__ ushortT p_sh[8 * 1280];            // per-wave dbuf slab [2][16][40]
    int tid = threadIdx.x, wave = tid >> 6, lane = tid & 63;
    int c = lane & 15, g = (lane >> 4) & 3;
    int s = blockIdx.x >> 3, h = blockIdx.x & 7;  // h = id&7: per-XCD h locality
    const ushortT* mrow = m + (size_t)s * R_ * CM;
    char* kb_ = (char*)k_sh;
    char* vb_ = (char*)vt_sh;
    char* psb = (char*)p_sh + wave * 2560;
    const f32x4 zero4 = {0.f, 0.f, 0.f, 0.f};

    for (int j = tid; j < R_; j += 512) mb[j] = 1e9f * (mask[s*R_ + j] - 1.0f);

    // ---- Phase 1: K,V GEMM for head h; wave owns rows wave*48 .. +47 ----
    const ushortT* wkb = wt + ((size_t)(256 + 2*h*16 + c)) * 256 + 8*g;   // mI=1
    const ushortT* wvb = wt + ((size_t)(512 + 2*h*16 + c)) * 256 + 8*g;   // mI=2
    #pragma unroll 1
    for (int rt = 0; rt < 3; ++rt) {
        int rbase = wave * 48 + rt * 16;
        bf16x8 afr[8];
        #pragma unroll
        for (int kc = 0; kc < 8; ++kc)
            afr[kc] = *(const bf16x8*)(mrow + (size_t)(rbase + c) * CM + kc*32 + 8*g);
        f32x4 ka0 = zero4, ka1 = zero4, va0 = zero4, va1 = zero4;
        #pragma unroll
        for (int kc = 0; kc < 8; ++kc) {
            bf16x8 bk0 = *(const bf16x8*)(wkb + kc*32);
            bf16x8 bk1 = *(const bf16x8*)(wkb + 16*256 + kc*32);
            bf16x8 bv0 = *(const bf16x8*)(wvb + kc*32);
            bf16x8 bv1 = *(const bf16x8*)(wvb + 16*256 + kc*32);
            ka0 = __builtin_amdgcn_mfma_f32_16x16x32_bf16(afr[kc], bk0, ka0, 0, 0, 0);
            ka1 = __builtin_amdgcn_mfma_f32_16x16x32_bf16(afr[kc], bk1, ka1, 0, 0, 0);
            va0 = __builtin_amdgcn_mfma_f32_16x16x32_bf16(afr[kc], bv0, va0, 0, 0, 0);
            va1 = __builtin_amdgcn_mfma_f32_16x16x32_bf16(afr[kc], bv1, va1, 0, 0, 0);
        }
        #pragma unroll
        for (int r = 0; r < 4; ++r) {
            int krow = rbase + 4*g + r;
            *(ushortT*)(kb_ + krow*80 + c*2)        = f2bf(ka0[r]);   // K[krow][c]
            *(ushortT*)(kb_ + krow*80 + (16+c)*2)   = f2bf(ka1[r]);   // K[krow][16+c]
            *(ushortT*)(vb_ + ((c*768      + krow*2) ^ ((c & 7) << 4))) = f2bf(va0[r]);
            *(ushortT*)(vb_ + (((16+c)*768 + krow*2) ^ ((c & 7) << 4))) = f2bf(va1[r]);
        }
    }
    __syncthreads();

    const char* ksb = (const char*)k_sh;
    const char* vtb = (const char*)vt_sh;

    // ---- Phase 2: attention per q-tile (3 per wave) ----
    for (int qt = wave; qt < 24; qt += 8) {
        int q0 = qt * 16;
        // q GEMM -> p-slab buffer 0 -> qf fragment
        bf16x8 afq[8];
        #pragma unroll
        for (int kc = 0; kc < 8; ++kc)
            afq[kc] = *(const bf16x8*)(mrow + (size_t)(q0 + c) * CM + kc*32 + 8*g);
        f32x4 qa0 = zero4, qa1 = zero4;
        const ushortT* wqb = wt + ((size_t)(2*h*16 + c)) * 256 + 8*g;    // mI=0 (pre-scaled)
        #pragma unroll
        for (int kc = 0; kc < 8; ++kc) {
            bf16x8 bq0 = *(const bf16x8*)(wqb + kc*32);
            bf16x8 bq1 = *(const bf16x8*)(wqb + 16*256 + kc*32);
            qa0 = __builtin_amdgcn_mfma_f32_16x16x32_bf16(afq[kc], bq0, qa0, 0, 0, 0);
            qa1 = __builtin_amdgcn_mfma_f32_16x16x32_bf16(afq[kc], bq1, qa1, 0, 0, 0);
        }
        #pragma unroll
        for (int r = 0; r < 4; ++r) {
            *(ushortT*)(psb + (4*g + r)*80 + c*2)      = f2bf(qa0[r]);  // Q[q0+4g+r][c]
            *(ushortT*)(psb + (4*g + r)*80 + (16+c)*2) = f2bf(qa1[r]);
        }
        bf16x8 qf = *(const bf16x8*)(psb + c*80 + 16*g);                 // Q[q0+c][8g..]
        const ushortT* zq = zws + (size_t)h * RRTOT + (size_t)(q0 + c) * R_ + 4*g;

        float sm = 0.f;
        f32x4 o0 = zero4, o1 = zero4;
        #pragma unroll 2
        for (int kb = 0; kb < 12; ++kb) {
            bf16x8 kfA = *(const bf16x8*)(ksb + ((2*kb    )*16 + c)*80 + 16*g);
            bf16x8 kfB = *(const bf16x8*)(ksb + ((2*kb + 1)*16 + c)*80 + 16*g);
            f32x4 pA = __builtin_amdgcn_mfma_f32_16x16x32_bf16(kfA, qf, zero4, 0, 0, 0);
            f32x4 pB = __builtin_amdgcn_mfma_f32_16x16x32_bf16(kfB, qf, zero4, 0, 0, 0);
            float4 mvA = *(const float4*)&mb[(2*kb    )*16 + 4*g];
            float4 mvB = *(const float4*)&mb[(2*kb + 1)*16 + 4*g];
            ushort4 zvA = *(const ushort4*)(zq + (2*kb    )*16);
            ushort4 zvB = *(const ushort4*)(zq + (2*kb + 1)*16);
            pA.x = __expf(pA.x + mvA.x + bf2f(zvA.x));
            pA.y = __expf(pA.y + mvA.y + bf2f(zvA.y));
            pA.z = __expf(pA.z + mvA.z + bf2f(zvA.z));
            pA.w = __expf(pA.w + mvA.w + bf2f(zvA.w));
            pB.x = __expf(pB.x + mvB.x + bf2f(zvB.x));
            pB.y = __expf(pB.y + mvB.y + bf2f(zvB.y));
            pB.z = __expf(pB.z + mvB.z + bf2f(zvB.z));
            pB.w = __expf(pB.w + mvB.w + bf2f(zvB.w));
            sm += (pA.x + pA.y) + (pA.z + pA.w) + (pB.x + pB.y) + (pB.z + pB.w);
            uint2 wA; wA.x = pack_bf2(pA.x, pA.y); wA.y = pack_bf2(pA.z, pA.w);
            uint2 wB; wB.x = pack_bf2(pB.x, pB.y); wB.y = pack_bf2(pB.z, pB.w);
            *(uint2*)(psb + (kb&1)*1280 + c*80 +      8*g) = wA;
            *(uint2*)(psb + (kb&1)*1280 + c*80 + 32 + 8*g) = wB;
            bf16x8 pa = *(const bf16x8*)(psb + (kb&1)*1280 + c*80 + 16*g);
            bf16x8 v0 = *(const bf16x8*)(vtb + (((c     )*768 + kb*64 + 16*g) ^ ((c & 7) << 4)));
            bf16x8 v1 = *(const bf16x8*)(vtb + (((16 + c)*768 + kb*64 + 16*g) ^ ((c & 7) << 4)));
            o0 = __builtin_amdgcn_mfma_f32_16x16x32_bf16(v0, pa, o0, 0, 0, 0);
            o1 = __builtin_amdgcn_mfma_f32_16x16x32_bf16(v1, pa, o1, 0, 0, 0);
        }
        sm += __shfl_xor(sm, 16);
        sm += __shfl_xor(sm, 32);
        float inv = 1.0f / sm;
        float4 s0, s1;
        s0.x = o0[0]*inv; s0.y = o0[1]*inv; s0.z = o0[2]*inv; s0.w = o0[3]*inv;
        s1.x = o1[0]*inv; s1.y = o1[1]*inv; s1.z = o1[2]*inv; s1.w = o1[3]*inv;
        float* ob = out + (size_t)(s*R_ + q0 + c) * CM + h*D_ + 4*g;
        *(float4*)ob = s0;
        *(float4*)(ob + 16) = s1;
    }
}

// ---------------------------------------------------------------------------
// 4-coltile MFMA group macro (r10-verified).
// ---------------------------------------------------------------------------
#define MFMA_GROUP4(AF, WB)                                                          \
    {                                                                                \
        _Pragma("unroll")                                                            \
        for (int kc = 0; kc < 8; ++kc) {                                             \
            bf16x8 b0 = *(const bf16x8*)((WB) + kc*32);                              \
            bf16x8 b1 = *(const bf16x8*)((WB) + 16*256 + kc*32);                     \
            bf16x8 b2 = *(const bf16x8*)((WB) + 32*256 + kc*32);                     \
            bf16x8 b3 = *(const bf16x8*)((WB) + 48*256 + kc*32);                     \
            a0L = __builtin_amdgcn_mfma_f32_16x16x32_bf16(AF[0][kc], b0, a0L, 0,0,0);\
            a0H = __builtin_amdgcn_mfma_f32_16x16x32_bf16(AF[1][kc], b0, a0H, 0,0,0);\
            a1L = __builtin_amdgcn_mfma_f32_16x16x32_bf16(AF[0][kc], b1, a1L, 0,0,0);\
            a1H = __builtin_amdgcn_mfma_f32_16x16x32_bf16(AF[1][kc], b1, a1H, 0,0,0);\
            a2L = __builtin_amdgcn_mfma_f32_16x16x32_bf16(AF[0][kc], b2, a2L, 0,0,0);\
            a2H = __builtin_amdgcn_mfma_f32_16x16x32_bf16(AF[1][kc], b2, a2H, 0,0,0);\
            a3L = __builtin_amdgcn_mfma_f32_16x16x32_bf16(AF[0][kc], b3, a3L, 0,0,0);\
            a3H = __builtin_amdgcn_mfma_f32_16x16x32_bf16(AF[1][kc], b3, a3H, 0,0,0);\
        }                                                                            \
    }

// ---------------------------------------------------------------------------
// K4: gating + output projection. r10's verified col-split structure (32 rows
// per block, 16 KB LDS, high occupancy) with the LN phase replaced by direct
// A-fragment loads from global m (r12-verified pattern).
// ---------------------------------------------------------------------------
__global__ __launch_bounds__(256) void k_out_m(
        const ushortT* __restrict__ m, const ushortT* __restrict__ wgt,
        const float* __restrict__ bg, const ushortT* __restrict__ wot,
        const float* __restrict__ bo, float* __restrict__ out) {
    __shared__ ushortT og_sh[32 * 256];
    int tid = threadIdx.x, wave = tid >> 6, lane = tid & 63;
    int c = lane & 15, g = (lane >> 4) & 3;
    int r0 = blockIdx.x * 32;
    char* ogb = (char*)og_sh;

    bf16x8 af[2][8];
    #pragma unroll
    for (int rt = 0; rt < 2; ++rt)
        #pragma unroll
        for (int kc = 0; kc < 8; ++kc)
            af[rt][kc] = *(const bf16x8*)(m + (size_t)(r0 + rt*16 + c) * CM + kc*32 + 8*g);

    const f32x4 z4 = {0.f, 0.f, 0.f, 0.f};
    {   // gating GEMM (4 tiles / wave) + o*g -> og_sh
        int tb = wave * 4;
        const ushortT* wb0 = wgt + (size_t)(tb*16 + c) * 256 + 8*g;
        f32x4 a0L = z4, a0H = z4, a1L = z4, a1H = z4;
        f32x4 a2L = z4, a2H = z4, a3L = z4, a3H = z4;
        MFMA_GROUP4(af, wb0);
        #pragma unroll
        for (int j = 0; j < 4; ++j) {
            f32x4 lo = (j == 0) ? a0L : (j == 1) ? a1L : (j == 2) ? a2L : a3L;
            f32x4 hi = (j == 0) ? a0H : (j == 1) ? a1H : (j == 2) ? a2H : a3H;
            int t = (tb + j)*16 + c;
            float bgv = bg[t];
            #pragma unroll
            for (int r = 0; r < 4; ++r) {
                int row0 = 4*g + r, row1 = row0 + 16;
                float g0 = 1.0f / (1.0f + __expf(-(lo[r] + bgv)));
                float g1 = 1.0f / (1.0f + __expf(-(hi[r] + bgv)));
                float ov0 = out[(size_t)(r0 + row0) * CM + t];
                float ov1 = out[(size_t)(r0 + row1) * CM + t];
                *(ushortT*)(ogb + ((row0*512 + t*2) ^ ((row0 & 7) << 4))) = f2bf(ov0 * g0);
                *(ushortT*)(ogb + ((row1*512 + t*2) ^ ((row1 & 7) << 4))) = f2bf(ov1 * g1);
            }
        }
    }
    __syncthreads();

    bf16x8 af2[2][8];
    #pragma unroll
    for (int rt = 0; rt < 2; ++rt)
        #pragma unroll
        for (int kc = 0; kc < 8; ++kc) {
            int row = rt*16 + c;
            af2[rt][kc] = *(const bf16x8*)(ogb + ((row*512 + (kc*32 + 8*g)*2) ^ ((c & 7) << 4)));
        }

    {   // output projection
        int tb = wave * 4;
        const ushortT* wb0 = wot + (size_t)(tb*16 + c) * 256 + 8*g;
        f32x4 a0L = z4, a0H = z4, a1L = z4, a1H = z4;
        f32x4 a2L = z4, a2H = z4, a3L = z4, a3H = z4;
        MFMA_GROUP4(af2, wb0);
        #pragma unroll
        for (int j = 0; j < 4; ++j) {
            f32x4 lo = (j == 0) ? a0L : (j == 1) ? a1L : (j == 2) ? a2L : a3L;
            f32x4 hi = (j == 0) ? a0H : (j == 1) ? a1H : (j == 2) ? a2H : a3H;
            int t = (tb + j)*16 + c;
            float bov = bo[t];
            #pragma unroll
            for (int r = 0; r < 4; ++r) {
                int row0 = 4*g + r, row1 = row0 + 16;
                out[(size_t)(r0 + row0) * CM + t] = lo[r] + bov;
                out[(size_t)(r0 + row1) * CM + t] = hi[r] + bov;
            }
        }
    }
}

// ---------------------------------------------------------------------------
extern "C" void kernel_launch(void* const* d_in, const int* in_sizes, int n_in,
                              void* d_out, int out_size, void* d_ws, size_t ws_size,
                              hipStream_t stream) {
    const float* msa    = (const float*)d_in[0];
    const float* pair   = (const float*)d_in[1];
    const float* mask   = (const float*)d_in[2];
    const float* qn_g   = (const float*)d_in[3];
    const float* qn_b   = (const float*)d_in[4];
    const float* pn_g   = (const float*)d_in[5];
    const float* pn_b   = (const float*)d_in[6];
    const float* w_pair = (const float*)d_in[7];
    const float* wq     = (const float*)d_in[8];
    const float* wk     = (const float*)d_in[9];
    const float* wv     = (const float*)d_in[10];
    const float* wg     = (const float*)d_in[11];
    const float* bg     = (const float*)d_in[12];
    const float* wo     = (const float*)d_in[13];
    const float* bo     = (const float*)d_in[14];
    float* out = (float*)d_out;

    ushortT* zws = (ushortT*)d_ws;                // [H][R][R] bf16, 2.36 MB
    ushortT* wt  = zws + (size_t)H_ * RRTOT;      // 3*256*256
    ushortT* wgt = wt + 3 * 65536;
    ushortT* wot = wgt + 65536;
    ushortT* mws = wot + 65536;                   // [SR][256] bf16, 25.2 MB

    k_prep     <<<1280,    256, 0, stream>>>(wq, wk, wv, wg, wo, wt, wgt, wot);
    k_pair_bias<<<RRTOT/4, 256, 0, stream>>>(pair, pn_g, pn_b, w_pair, zws);
    k_ln       <<<SR/32,   256, 0, stream>>>(msa, qn_g, qn_b, mws);
    k_attn_f   <<<S_*H_,   512, 0, stream>>>(mws, wt, zws, mask, out);
    k_out_m    <<<SR/32,   256, 0, stream>>>(mws, wgt, bg, wot, bo, out);
}

// Round 14
// 289.089 us; speedup vs baseline: 1.1760x; 1.0093x over previous
//
#include <hip/hip_runtime.h>
#include <hip/hip_bf16.h>

typedef unsigned int uint;
typedef unsigned short ushortT;
typedef __attribute__((ext_vector_type(8))) short bf16x8;
typedef __attribute__((ext_vector_type(4))) float f32x4;

#define S_ 128
#define R_ 384
#define CM 256
#define CZ 128
#define H_ 8
#define D_ 32
#define SR (S_*R_)          // 49152
#define RRTOT (R_*R_)       // 147456

__device__ __forceinline__ float bf2f(ushortT u) {
    return __uint_as_float(((uint)u) << 16);
}
__device__ __forceinline__ ushortT f2bf(float f) {
    uint x = __float_as_uint(f);
    x += 0x7FFFu + ((x >> 16) & 1u);   // RNE
    return (ushortT)(x >> 16);
}
__device__ __forceinline__ uint pack_bf2(float lo, float hi) {
    return (uint)f2bf(lo) | ((uint)f2bf(hi) << 16);
}

// ---------------------------------------------------------------------------
// K0: weight prep — transpose + bf16-ify all projection weights.
// wt[mI*256 + t][c] = w_mI[c][t]; mI=0 q-scaled, 1 k, 2 v. wgt/wot likewise.
// ---------------------------------------------------------------------------
__global__ __launch_bounds__(256) void k_prep(
        const float* __restrict__ wq, const float* __restrict__ wk,
        const float* __restrict__ wv, const float* __restrict__ wg,
        const float* __restrict__ wo,
        ushortT* __restrict__ wt, ushortT* __restrict__ wgt,
        ushortT* __restrict__ wot) {
    int id = blockIdx.x * 256 + threadIdx.x;      // 5*65536 total
    int which = id >> 16, r16 = id & 65535;
    int y = r16 & 255, x = r16 >> 8;              // y = coalesced src fast dim
    if (which == 0)      wt[(size_t)y*256 + x]       = f2bf(wq[(size_t)x*256 + y] * 0.17677669529663687f);
    else if (which == 1) wt[(size_t)(256+y)*256 + x] = f2bf(wk[(size_t)x*256 + y]);
    else if (which == 2) wt[(size_t)(512+y)*256 + x] = f2bf(wv[(size_t)x*256 + y]);
    else if (which == 3) wgt[(size_t)y*256 + x]      = f2bf(wg[(size_t)x*256 + y]);
    else                 wot[(size_t)y*256 + x]      = f2bf(wo[(size_t)x*256 + y]);
}

// ---------------------------------------------------------------------------
// K1: pair LN + projection to z[h][i][j] (bf16). One wave per (i,j) row.
// ---------------------------------------------------------------------------
__global__ __launch_bounds__(256) void k_pair_bias(
        const float* __restrict__ pair, const float* __restrict__ pn_g,
        const float* __restrict__ pn_b, const float* __restrict__ w_pair,
        ushortT* __restrict__ z) {
    int wave = threadIdx.x >> 6, lane = threadIdx.x & 63;
    int row = blockIdx.x * 4 + wave;              // [0, R*R)
    const float* x = pair + (size_t)row * CZ;
    float2 xv = *(const float2*)&x[lane * 2];
    float s  = xv.x + xv.y;
    float s2 = xv.x*xv.x + xv.y*xv.y;
    #pragma unroll
    for (int off = 32; off; off >>= 1) {
        s  += __shfl_xor(s,  off);
        s2 += __shfl_xor(s2, off);
    }
    float mu  = s * (1.0f / 128.0f);
    float var = s2 * (1.0f / 128.0f) - mu * mu;
    float rstd = rsqrtf(var + 1e-5f);
    float2 gv = *(const float2*)&pn_g[lane * 2];
    float2 bv = *(const float2*)&pn_b[lane * 2];
    float n0 = (xv.x - mu) * rstd * gv.x + bv.x;
    float n1 = (xv.y - mu) * rstd * gv.y + bv.y;
    float4 wa = *(const float4*)&w_pair[lane*16     ];
    float4 wb = *(const float4*)&w_pair[lane*16 +  4];
    float4 wc = *(const float4*)&w_pair[lane*16 +  8];
    float4 wd = *(const float4*)&w_pair[lane*16 + 12];
    float v0_ = n0*wa.x + n1*wc.x, v1_ = n0*wa.y + n1*wc.y;
    float v2_ = n0*wa.z + n1*wc.z, v3_ = n0*wa.w + n1*wc.w;
    float v4_ = n0*wb.x + n1*wd.x, v5_ = n0*wb.y + n1*wd.y;
    float v6_ = n0*wb.z + n1*wd.z, v7_ = n0*wb.w + n1*wd.w;
    float x0 = __shfl_xor(v0_,1), x1 = __shfl_xor(v1_,1), x2 = __shfl_xor(v2_,1), x3 = __shfl_xor(v3_,1);
    float x4 = __shfl_xor(v4_,1), x5 = __shfl_xor(v5_,1), x6 = __shfl_xor(v6_,1), x7 = __shfl_xor(v7_,1);
    bool b0 = (lane & 1) != 0;
    float u0 = b0 ? v4_+x4 : v0_+x0;
    float u1 = b0 ? v5_+x5 : v1_+x1;
    float u2 = b0 ? v6_+x6 : v2_+x2;
    float u3 = b0 ? v7_+x7 : v3_+x3;
    float y0 = __shfl_xor(u0,2), y1 = __shfl_xor(u1,2), y2 = __shfl_xor(u2,2), y3 = __shfl_xor(u3,2);
    bool b1 = (lane & 2) != 0;
    float w0 = b1 ? u2+y2 : u0+y0;
    float w1 = b1 ? u3+y3 : u1+y1;
    float z0 = __shfl_xor(w0,4), z1 = __shfl_xor(w1,4);
    bool b2 = (lane & 4) != 0;
    float val = b2 ? w1+z1 : w0+z0;
    val += __shfl_xor(val, 8);
    val += __shfl_xor(val, 16);
    val += __shfl_xor(val, 32);
    int hmap = 4*(lane & 1) + 2*((lane >> 1) & 1) + ((lane >> 2) & 1);
    if (lane < 8) z[(size_t)hmap * RRTOT + row] = f2bf(val);
}

// ---------------------------------------------------------------------------
// LN reduce helper (E[x^2]-mu^2 fused butterfly) -> packed bf16 uint2
// ---------------------------------------------------------------------------
__device__ __forceinline__ uint2 ln_reduce(float4 xv, float4 gv, float4 bv) {
    float sm = (xv.x + xv.y) + (xv.z + xv.w);
    float s2 = (xv.x*xv.x + xv.y*xv.y) + (xv.z*xv.z + xv.w*xv.w);
    #pragma unroll
    for (int off = 32; off; off >>= 1) {
        sm += __shfl_xor(sm, off);
        s2 += __shfl_xor(s2, off);
    }
    float mu  = sm * (1.0f / 256.0f);
    float var = s2 * (1.0f / 256.0f) - mu * mu;
    float rstd = rsqrtf(var + 1e-5f);
    uint2 w;
    w.x = pack_bf2((xv.x - mu)*rstd*gv.x + bv.x, (xv.y - mu)*rstd*gv.y + bv.y);
    w.y = pack_bf2((xv.z - mu)*rstd*gv.z + bv.z, (xv.w - mu)*rstd*gv.w + bv.w);
    return w;
}

// ---------------------------------------------------------------------------
// K_LN: streaming LN of msa -> m (bf16, row-major [SR][256]). (r12-verified)
// ---------------------------------------------------------------------------
__global__ __launch_bounds__(256) void k_ln(
        const float* __restrict__ msa, const float* __restrict__ qn_g,
        const float* __restrict__ qn_b, ushortT* __restrict__ m) {
    int wave = threadIdx.x >> 6, lane = threadIdx.x & 63;
    int r0 = blockIdx.x * 32 + wave * 8;
    const float* src = msa + (size_t)r0 * CM + lane * 4;
    float4 x0 = *(const float4*)(src        );
    float4 x1 = *(const float4*)(src + 1*CM );
    float4 x2 = *(const float4*)(src + 2*CM );
    float4 x3 = *(const float4*)(src + 3*CM );
    float4 x4 = *(const float4*)(src + 4*CM );
    float4 x5 = *(const float4*)(src + 5*CM );
    float4 x6 = *(const float4*)(src + 6*CM );
    float4 x7 = *(const float4*)(src + 7*CM );
    float4 gv = *(const float4*)&qn_g[lane*4];
    float4 bv = *(const float4*)&qn_b[lane*4];
    ushortT* dst = m + (size_t)r0 * CM + lane * 4;
    *(uint2*)(dst       ) = ln_reduce(x0, gv, bv);
    *(uint2*)(dst + 1*CM) = ln_reduce(x1, gv, bv);
    *(uint2*)(dst + 2*CM) = ln_reduce(x2, gv, bv);
    *(uint2*)(dst + 3*CM) = ln_reduce(x3, gv, bv);
    *(uint2*)(dst + 4*CM) = ln_reduce(x4, gv, bv);
    *(uint2*)(dst + 5*CM) = ln_reduce(x5, gv, bv);
    *(uint2*)(dst + 6*CM) = ln_reduce(x6, gv, bv);
    *(uint2*)(dst + 7*CM) = ln_reduce(x7, gv, bv);
}

// ---------------------------------------------------------------------------
// K3f: FUSED q/k/v projection + attention, per (s,h). 8 waves.
// DECODE: s = id&127, h = id>>7 — all 8 h-blocks of a given s land on the
// SAME XCD (id mod 8 == s mod 8), so each XCD's 16 m-slices (3.1 MB) stay
// L2-resident across all h-passes: m fetched ~once per XCD (r13 fetched 8x).
// Phase 1/2 and the kb loop are byte-identical to r13 (verified).
// ---------------------------------------------------------------------------
__global__ __launch_bounds__(512) void k_attn_f(
        const ushortT* __restrict__ m, const ushortT* __restrict__ wt,
        const ushortT* __restrict__ zws, const float* __restrict__ mask,
        float* __restrict__ out) {
    __shared__ ushortT k_sh[R_ * 40];             // [k][d] rows padded to 80 B
    __shared__ ushortT vt_sh[D_ * R_];            // [d][k] XOR ((d&7)<<4)
    __shared__ float   mb[R_];
    __shared__ ushortT p_sh[8 * 1280];            // per-wave dbuf slab [2][16][40]
    int tid = threadIdx.x, wave = tid >> 6, lane = tid & 63;
    int c = lane & 15, g = (lane >> 4) & 3;
    int s = blockIdx.x & 127, h = blockIdx.x >> 7;  // same-s blocks -> same XCD
    const ushortT* mrow = m + (size_t)s * R_ * CM;
    char* kb_ = (char*)k_sh;
    char* vb_ = (char*)vt_sh;
    char* psb = (char*)p_sh + wave * 2560;
    const f32x4 zero4 = {0.f, 0.f, 0.f, 0.f};

    for (int j = tid; j < R_; j += 512) mb[j] = 1e9f * (mask[s*R_ + j] - 1.0f);

    // ---- Phase 1: K,V GEMM for head h; wave owns rows wave*48 .. +47 ----
    const ushortT* wkb = wt + ((size_t)(256 + 2*h*16 + c)) * 256 + 8*g;   // mI=1
    const ushortT* wvb = wt + ((size_t)(512 + 2*h*16 + c)) * 256 + 8*g;   // mI=2
    #pragma unroll 1
    for (int rt = 0; rt < 3; ++rt) {
        int rbase = wave * 48 + rt * 16;
        bf16x8 afr[8];
        #pragma unroll
        for (int kc = 0; kc < 8; ++kc)
            afr[kc] = *(const bf16x8*)(mrow + (size_t)(rbase + c) * CM + kc*32 + 8*g);
        f32x4 ka0 = zero4, ka1 = zero4, va0 = zero4, va1 = zero4;
        #pragma unroll
        for (int kc = 0; kc < 8; ++kc) {
            bf16x8 bk0 = *(const bf16x8*)(wkb + kc*32);
            bf16x8 bk1 = *(const bf16x8*)(wkb + 16*256 + kc*32);
            bf16x8 bv0 = *(const bf16x8*)(wvb + kc*32);
            bf16x8 bv1 = *(const bf16x8*)(wvb + 16*256 + kc*32);
            ka0 = __builtin_amdgcn_mfma_f32_16x16x32_bf16(afr[kc], bk0, ka0, 0, 0, 0);
            ka1 = __builtin_amdgcn_mfma_f32_16x16x32_bf16(afr[kc], bk1, ka1, 0, 0, 0);
            va0 = __builtin_amdgcn_mfma_f32_16x16x32_bf16(afr[kc], bv0, va0, 0, 0, 0);
            va1 = __builtin_amdgcn_mfma_f32_16x16x32_bf16(afr[kc], bv1, va1, 0, 0, 0);
        }
        #pragma unroll
        for (int r = 0; r < 4; ++r) {
            int krow = rbase + 4*g + r;
            *(ushortT*)(kb_ + krow*80 + c*2)        = f2bf(ka0[r]);   // K[krow][c]
            *(ushortT*)(kb_ + krow*80 + (16+c)*2)   = f2bf(ka1[r]);   // K[krow][16+c]
            *(ushortT*)(vb_ + ((c*768      + krow*2) ^ ((c & 7) << 4))) = f2bf(va0[r]);
            *(ushortT*)(vb_ + (((16+c)*768 + krow*2) ^ ((c & 7) << 4))) = f2bf(va1[r]);
        }
    }
    __syncthreads();

    const char* ksb = (const char*)k_sh;
    const char* vtb = (const char*)vt_sh;

    // ---- Phase 2: attention per q-tile (3 per wave) ----
    for (int qt = wave; qt < 24; qt += 8) {
        int q0 = qt * 16;
        // q GEMM -> p-slab buffer 0 -> qf fragment
        bf16x8 afq[8];
        #pragma unroll
        for (int kc = 0; kc < 8; ++kc)
            afq[kc] = *(const bf16x8*)(mrow + (size_t)(q0 + c) * CM + kc*32 + 8*g);
        f32x4 qa0 = zero4, qa1 = zero4;
        const ushortT* wqb = wt + ((size_t)(2*h*16 + c)) * 256 + 8*g;    // mI=0 (pre-scaled)
        #pragma unroll
        for (int kc = 0; kc < 8; ++kc) {
            bf16x8 bq0 = *(const bf16x8*)(wqb + kc*32);
            bf16x8 bq1 = *(const bf16x8*)(wqb + 16*256 + kc*32);
            qa0 = __builtin_amdgcn_mfma_f32_16x16x32_bf16(afq[kc], bq0, qa0, 0, 0, 0);
            qa1 = __builtin_amdgcn_mfma_f32_16x16x32_bf16(afq[kc], bq1, qa1, 0, 0, 0);
        }
        #pragma unroll
        for (int r = 0; r < 4; ++r) {
            *(ushortT*)(psb + (4*g + r)*80 + c*2)      = f2bf(qa0[r]);  // Q[q0+4g+r][c]
            *(ushortT*)(psb + (4*g + r)*80 + (16+c)*2) = f2bf(qa1[r]);
        }
        bf16x8 qf = *(const bf16x8*)(psb + c*80 + 16*g);                 // Q[q0+c][8g..]
        const ushortT* zq = zws + (size_t)h * RRTOT + (size_t)(q0 + c) * R_ + 4*g;

        float sm = 0.f;
        f32x4 o0 = zero4, o1 = zero4;
        #pragma unroll 2
        for (int kb = 0; kb < 12; ++kb) {
            bf16x8 kfA = *(const bf16x8*)(ksb + ((2*kb    )*16 + c)*80 + 16*g);
            bf16x8 kfB = *(const bf16x8*)(ksb + ((2*kb + 1)*16 + c)*80 + 16*g);
            f32x4 pA = __builtin_amdgcn_mfma_f32_16x16x32_bf16(kfA, qf, zero4, 0, 0, 0);
            f32x4 pB = __builtin_amdgcn_mfma_f32_16x16x32_bf16(kfB, qf, zero4, 0, 0, 0);
            float4 mvA = *(const float4*)&mb[(2*kb    )*16 + 4*g];
            float4 mvB = *(const float4*)&mb[(2*kb + 1)*16 + 4*g];
            ushort4 zvA = *(const ushort4*)(zq + (2*kb    )*16);
            ushort4 zvB = *(const ushort4*)(zq + (2*kb + 1)*16);
            pA.x = __expf(pA.x + mvA.x + bf2f(zvA.x));
            pA.y = __expf(pA.y + mvA.y + bf2f(zvA.y));
            pA.z = __expf(pA.z + mvA.z + bf2f(zvA.z));
            pA.w = __expf(pA.w + mvA.w + bf2f(zvA.w));
            pB.x = __expf(pB.x + mvB.x + bf2f(zvB.x));
            pB.y = __expf(pB.y + mvB.y + bf2f(zvB.y));
            pB.z = __expf(pB.z + mvB.z + bf2f(zvB.z));
            pB.w = __expf(pB.w + mvB.w + bf2f(zvB.w));
            sm += (pA.x + pA.y) + (pA.z + pA.w) + (pB.x + pB.y) + (pB.z + pB.w);
            uint2 wA; wA.x = pack_bf2(pA.x, pA.y); wA.y = pack_bf2(pA.z, pA.w);
            uint2 wB; wB.x = pack_bf2(pB.x, pB.y); wB.y = pack_bf2(pB.z, pB.w);
            *(uint2*)(psb + (kb&1)*1280 + c*80 +      8*g) = wA;
            *(uint2*)(psb + (kb&1)*1280 + c*80 + 32 + 8*g) = wB;
            bf16x8 pa = *(const bf16x8*)(psb + (kb&1)*1280 + c*80 + 16*g);
            bf16x8 v0 = *(const bf16x8*)(vtb + (((c     )*768 + kb*64 + 16*g) ^ ((c & 7) << 4)));
            bf16x8 v1 = *(const bf16x8*)(vtb + (((16 + c)*768 + kb*64 + 16*g) ^ ((c & 7) << 4)));
            o0 = __builtin_amdgcn_mfma_f32_16x16x32_bf16(v0, pa, o0, 0, 0, 0);
            o1 = __builtin_amdgcn_mfma_f32_16x16x32_bf16(v1, pa, o1, 0, 0, 0);
        }
        sm += __shfl_xor(sm, 16);
        sm += __shfl_xor(sm, 32);
        float inv = 1.0f / sm;
        float4 s0, s1;
        s0.x = o0[0]*inv; s0.y = o0[1]*inv; s0.z = o0[2]*inv; s0.w = o0[3]*inv;
        s1.x = o1[0]*inv; s1.y = o1[1]*inv; s1.z = o1[2]*inv; s1.w = o1[3]*inv;
        float* ob = out + (size_t)(s*R_ + q0 + c) * CM + h*D_ + 4*g;
        *(float4*)ob = s0;
        *(float4*)(ob + 16) = s1;
    }
}

// ---------------------------------------------------------------------------
// 4-coltile MFMA group macro (r10-verified).
// ---------------------------------------------------------------------------
#define MFMA_GROUP4(AF, WB)                                                          \
    {                                                                                \
        _Pragma("unroll")                                                            \
        for (int kc = 0; kc < 8; ++kc) {                                             \
            bf16x8 b0 = *(const bf16x8*)((WB) + kc*32);                              \
            bf16x8 b1 = *(const bf16x8*)((WB) + 16*256 + kc*32);                     \
            bf16x8 b2 = *(const bf16x8*)((WB) + 32*256 + kc*32);                     \
            bf16x8 b3 = *(const bf16x8*)((WB) + 48*256 + kc*32);                     \
            a0L = __builtin_amdgcn_mfma_f32_16x16x32_bf16(AF[0][kc], b0, a0L, 0,0,0);\
            a0H = __builtin_amdgcn_mfma_f32_16x16x32_bf16(AF[1][kc], b0, a0H, 0,0,0);\
            a1L = __builtin_amdgcn_mfma_f32_16x16x32_bf16(AF[0][kc], b1, a1L, 0,0,0);\
            a1H = __builtin_amdgcn_mfma_f32_16x16x32_bf16(AF[1][kc], b1, a1H, 0,0,0);\
            a2L = __builtin_amdgcn_mfma_f32_16x16x32_bf16(AF[0][kc], b2, a2L, 0,0,0);\
            a2H = __builtin_amdgcn_mfma_f32_16x16x32_bf16(AF[1][kc], b2, a2H, 0,0,0);\
            a3L = __builtin_amdgcn_mfma_f32_16x16x32_bf16(AF[0][kc], b3, a3L, 0,0,0);\
            a3H = __builtin_amdgcn_mfma_f32_16x16x32_bf16(AF[1][kc], b3, a3H, 0,0,0);\
        }                                                                            \
    }

// ---------------------------------------------------------------------------
// K4: gating + output projection. r10's verified col-split structure (32 rows
// per block, 16 KB LDS, high occupancy) with the LN phase replaced by direct
// A-fragment loads from global m (r12/r13-verified pattern).
// ---------------------------------------------------------------------------
__global__ __launch_bounds__(256) void k_out_m(
        const ushortT* __restrict__ m, const ushortT* __restrict__ wgt,
        const float* __restrict__ bg, const ushortT* __restrict__ wot,
        const float* __restrict__ bo, float* __restrict__ out) {
    __shared__ ushortT og_sh[32 * 256];
    int tid = threadIdx.x, wave = tid >> 6, lane = tid & 63;
    int c = lane & 15, g = (lane >> 4) & 3;
    int r0 = blockIdx.x * 32;
    char* ogb = (char*)og_sh;

    bf16x8 af[2][8];
    #pragma unroll
    for (int rt = 0; rt < 2; ++rt)
        #pragma unroll
        for (int kc = 0; kc < 8; ++kc)
            af[rt][kc] = *(const bf16x8*)(m + (size_t)(r0 + rt*16 + c) * CM + kc*32 + 8*g);

    const f32x4 z4 = {0.f, 0.f, 0.f, 0.f};
    {   // gating GEMM (4 tiles / wave) + o*g -> og_sh
        int tb = wave * 4;
        const ushortT* wb0 = wgt + (size_t)(tb*16 + c) * 256 + 8*g;
        f32x4 a0L = z4, a0H = z4, a1L = z4, a1H = z4;
        f32x4 a2L = z4, a2H = z4, a3L = z4, a3H = z4;
        MFMA_GROUP4(af, wb0);
        #pragma unroll
        for (int j = 0; j < 4; ++j) {
            f32x4 lo = (j == 0) ? a0L : (j == 1) ? a1L : (j == 2) ? a2L : a3L;
            f32x4 hi = (j == 0) ? a0H : (j == 1) ? a1H : (j == 2) ? a2H : a3H;
            int t = (tb + j)*16 + c;
            float bgv = bg[t];
            #pragma unroll
            for (int r = 0; r < 4; ++r) {
                int row0 = 4*g + r, row1 = row0 + 16;
                float g0 = 1.0f / (1.0f + __expf(-(lo[r] + bgv)));
                float g1 = 1.0f / (1.0f + __expf(-(hi[r] + bgv)));
                float ov0 = out[(size_t)(r0 + row0) * CM + t];
                float ov1 = out[(size_t)(r0 + row1) * CM + t];
                *(ushortT*)(ogb + ((row0*512 + t*2) ^ ((row0 & 7) << 4))) = f2bf(ov0 * g0);
                *(ushortT*)(ogb + ((row1*512 + t*2) ^ ((row1 & 7) << 4))) = f2bf(ov1 * g1);
            }
        }
    }
    __syncthreads();

    bf16x8 af2[2][8];
    #pragma unroll
    for (int rt = 0; rt < 2; ++rt)
        #pragma unroll
        for (int kc = 0; kc < 8; ++kc) {
            int row = rt*16 + c;
            af2[rt][kc] = *(const bf16x8*)(ogb + ((row*512 + (kc*32 + 8*g)*2) ^ ((c & 7) << 4)));
        }

    {   // output projection
        int tb = wave * 4;
        const ushortT* wb0 = wot + (size_t)(tb*16 + c) * 256 + 8*g;
        f32x4 a0L = z4, a0H = z4, a1L = z4, a1H = z4;
        f32x4 a2L = z4, a2H = z4, a3L = z4, a3H = z4;
        MFMA_GROUP4(af2, wb0);
        #pragma unroll
        for (int j = 0; j < 4; ++j) {
            f32x4 lo = (j == 0) ? a0L : (j == 1) ? a1L : (j == 2) ? a2L : a3L;
            f32x4 hi = (j == 0) ? a0H : (j == 1) ? a1H : (j == 2) ? a2H : a3H;
            int t = (tb + j)*16 + c;
            float bov = bo[t];
            #pragma unroll
            for (int r = 0; r < 4; ++r) {
                int row0 = 4*g + r, row1 = row0 + 16;
                out[(size_t)(r0 + row0) * CM + t] = lo[r] + bov;
                out[(size_t)(r0 + row1) * CM + t] = hi[r] + bov;
            }
        }
    }
}

// ---------------------------------------------------------------------------
extern "C" void kernel_launch(void* const* d_in, const int* in_sizes, int n_in,
                              void* d_out, int out_size, void* d_ws, size_t ws_size,
                              hipStream_t stream) {
    const float* msa    = (const float*)d_in[0];
    const float* pair   = (const float*)d_in[1];
    const float* mask   = (const float*)d_in[2];
    const float* qn_g   = (const float*)d_in[3];
    const float* qn_b   = (const float*)d_in[4];
    const float* pn_g   = (const float*)d_in[5];
    const float* pn_b   = (const float*)d_in[6];
    const float* w_pair = (const float*)d_in[7];
    const float* wq     = (const float*)d_in[8];
    const float* wk     = (const float*)d_in[9];
    const float* wv     = (const float*)d_in[10];
    const float* wg     = (const float*)d_in[11];
    const float* bg     = (const float*)d_in[12];
    const float* wo     = (const float*)d_in[13];
    const float* bo     = (const float*)d_in[14];
    float* out = (float*)d_out;

    ushortT* zws = (ushortT*)d_ws;                // [H][R][R] bf16, 2.36 MB
    ushortT* wt  = zws + (size_t)H_ * RRTOT;      // 3*256*256
    ushortT* wgt = wt + 3 * 65536;
    ushortT* wot = wgt + 65536;
    ushortT* mws = wot + 65536;                   // [SR][256] bf16, 25.2 MB

    k_prep     <<<1280,    256, 0, stream>>>(wq, wk, wv, wg, wo, wt, wgt, wot);
    k_pair_bias<<<RRTOT/4, 256, 0, stream>>>(pair, pn_g, pn_b, w_pair, zws);
    k_ln       <<<SR/32,   256, 0, stream>>>(msa, qn_g, qn_b, mws);
    k_attn_f   <<<S_*H_,   512, 0, stream>>>(mws, wt, zws, mask, out);
    k_out_m    <<<SR/32,   256, 0, stream>>>(mws, wgt, bg, wot, bo, out);
}